// Round 14
// baseline (56.113 us; speedup 1.0000x reference)
//
#include <hip/hip_runtime.h>
#include <hip/hip_bf16.h>

// MultiScaleSparseSelfAttention, algebraically reduced (25 attn -> 4/head).
// R8 bf16 best: 47.9us. R13 all-fp8: absmax 0.03125 vs thr 0.0267 (FAIL).
// Error budget (validated vs measurement to 1%):
//   sqrt(W-quant 0.0216^2 + P-quant 0.0216^2 + base 0.0078^2) = 0.0315.
// R14: R13 + P-CENTERING: pack (P-1) in fp8 (P~1+-0.17 -> 6x smaller quant
//      error), add rank-1 correction Wtot_d = 5*sum_n V[n][d] to pv
//      (new vtot_k). Predicted absmax ~0.0235. Keeps 2x byte reduction.

typedef __bf16 bf16x8 __attribute__((ext_vector_type(8)));
typedef __bf16 bf16x4 __attribute__((ext_vector_type(4)));
typedef float f32x4 __attribute__((ext_vector_type(4)));
typedef long i64;

#define MFMA16(A,B,C) __builtin_amdgcn_mfma_f32_16x16x32_bf16(A,B,C,0,0,0)
#define MFMA8(A,B,C)  __builtin_amdgcn_mfma_f32_16x16x32_fp8_fp8(A,B,C,0,0,0)

__device__ __forceinline__ bf16x8 ld8(const __bf16* p){ return *reinterpret_cast<const bf16x8*>(p); }
__device__ __forceinline__ i64 ldl(const unsigned char* p){ return *reinterpret_cast<const i64*>(p); }
__device__ __forceinline__ unsigned char tofp8(float v){
    return (unsigned char)(__builtin_amdgcn_cvt_pk_fp8_f32(v, v, 0, false) & 0xff);
}

struct ProjArgs { const float* W[6]; const float* Bz[6]; };

// ---- cvt: f32 -> bf16 in FRAGMENT order. X: 2x(2048x256), W: 6x(256x256) ----
__global__ __launch_bounds__(256) void cvt_k(const float* __restrict__ x0,
                                             const float* __restrict__ x1,
                                             ProjArgs args,
                                             __bf16* __restrict__ Xb,
                                             __bf16* __restrict__ Wb)
{
    int g = blockIdx.x*256 + threadIdx.x;
    const float* src; __bf16* dst;
    if (g < 131072){                           // X part: s = g>>16
        int s = g >> 16;
        int E = (g & 65535)*8;                 // element offset within scale
        int blk = E >> 9, lane8 = (E >> 3) & 63;
        int row = (blk>>3)*16 + (lane8 & 15);
        int ci  = (blk&7)*32 + (lane8>>4)*8;
        src = (s ? x1 : x0) + (size_t)row*256 + ci;
        dst = Xb + (size_t)s*524288 + E;
    } else {
        int gw = g - 131072;                   // W part: sp = gw>>13
        int sp = gw >> 13;
        int E = (gw & 8191)*8;
        int blk = E >> 9, lane8 = (E >> 3) & 63;
        int co = (blk>>3)*16 + (lane8 & 15);
        int ci = (blk&7)*32 + (lane8>>4)*8;
        src = args.W[sp] + (size_t)co*256 + ci;
        dst = Wb + (size_t)sp*65536 + E;
    }
    f32x4 a = *reinterpret_cast<const f32x4*>(src);
    f32x4 b = *reinterpret_cast<const f32x4*>(src+4);
    bf16x8 o;
    #pragma unroll
    for (int j=0;j<4;j++){ o[j] = (__bf16)a[j]; o[4+j] = (__bf16)b[j]; }
    *reinterpret_cast<bf16x8*>(dst) = o;
}

// ---------------- projection ----------------
// 64x64 tile per block; q/k -> fp8 fragment order (4KB), v -> bf16 natural
// (8KB); staged in LDS, written as one contiguous region.
__global__ __launch_bounds__(256) void proj_k(const __bf16* __restrict__ Xb,
                                              const __bf16* __restrict__ Wb,
                                              ProjArgs args,
                                              unsigned char* __restrict__ Qb,
                                              unsigned char* __restrict__ Kb,
                                              __bf16* __restrict__ Vb)
{
    __shared__ alignas(16) unsigned char stage[8192];
    int bid = blockIdx.x;
    int cg = bid % 12, rg = bid / 12;
    int tid = threadIdx.x, wv = tid >> 6, l = tid & 63;
    int lr = l & 15, lg = l >> 4;
    int s = rg >> 5;
    const __bf16* Xf = Xb + (size_t)s*524288;
    int p = cg >> 2;                       // 0=q 1=k 2=v
    const __bf16* Wf = Wb + (size_t)(s*3+p)*65536;
    const float* bp = args.Bz[s*3 + p];
    int colbase = (cg & 3)*64;
    int rowblk = ((rg & 31)*4 + wv);

    f32x4 acc[4];
    #pragma unroll
    for (int t=0;t<4;t++) acc[t] = f32x4{0.f,0.f,0.f,0.f};

    #pragma unroll
    for (int kk=0; kk<8; kk++){
        bf16x8 af = ld8(Xf + (size_t)(rowblk*8 + kk)*512 + l*8);
        #pragma unroll
        for (int ct=0; ct<4; ct++){
            bf16x8 bfv = ld8(Wf + (size_t)(((cg&3)*4 + ct)*8 + kk)*512 + l*8);
            acc[ct] = MFMA16(af, bfv, acc[ct]);
        }
    }
    // sqrt((1/16)*log2 e) folded into BOTH q and k before fp8 quantization
    float qs = (p < 2) ? 0.30028057f : 1.0f;
    #pragma unroll
    for (int ct=0; ct<4; ct++){
        int d = ct*16 + lr;                      // 0..63 within head
        float bias = bp[colbase + d];
        #pragma unroll
        for (int i=0;i<4;i++){
            float v = (acc[ct][i] + bias) * qs;
            if (p < 2){
                int a = wv*1024 + ((d>>5)&1)*512 + ((d>>3)&3)*128 + (lg*4+i)*8 + (d&7);
                stage[a] = tofp8(v);
            } else {
                __bf16* sh = reinterpret_cast<__bf16*>(stage);
                sh[(wv*16 + lg*4 + i)*64 + d] = (__bf16)v;
            }
        }
    }
    __syncthreads();
    int gr0 = rg*64;
    int b = (gr0 >> 10) & 1, n0 = gr0 & 1023;
    int h = cg & 3;
    int sb = s*2 + b;
    if (p < 2){
        unsigned char* dstb = (p==0) ? Qb : Kb;
        size_t goff = ((size_t)(sb*4 + h))*65536 + (size_t)(n0>>4)*1024;
        uint4 v = *reinterpret_cast<const uint4*>(stage + tid*16);
        *reinterpret_cast<uint4*>(dstb + goff + (size_t)tid*16) = v;
    } else {
        size_t goff = ((size_t)(sb*4 + h)*1024 + n0)*64;
        const __bf16* sh = reinterpret_cast<const __bf16*>(stage);
        bf16x8 v0 = *reinterpret_cast<const bf16x8*>(sh + tid*16);
        bf16x8 v1 = *reinterpret_cast<const bf16x8*>(sh + tid*16 + 8);
        *reinterpret_cast<bf16x8*>(Vb + goff + (size_t)tid*16)     = v0;
        *reinterpret_cast<bf16x8*>(Vb + goff + (size_t)tid*16 + 8) = v1;
    }
}

// ------ Wtot[sbu][d] = 5 * sum_n V[n][d]  (P-centering rank-1 term) ------
__global__ __launch_bounds__(256) void vtot_k(const __bf16* __restrict__ Vb,
                                              float* __restrict__ Wtot)
{
    __shared__ float red[4][64];
    int sbu = blockIdx.x, tid = threadIdx.x;
    int d = tid & 63, seg = tid >> 6;
    const __bf16* Vs = Vb + (size_t)sbu*65536;
    float sum = 0.f;
    for (int n = seg*256; n < seg*256 + 256; ++n)
        sum += (float)Vs[(size_t)n*64 + d];
    red[seg][d] = sum;
    __syncthreads();
    if (seg == 0)
        Wtot[(size_t)sbu*64 + d] = 5.f*(red[0][d]+red[1][d]+red[2][d]+red[3][d]);
}

// ------ smoothed V^T, sigma-permuted A-fragment order, fp8: Wsig[sbu] ------
__global__ __launch_bounds__(256) void smooth_k(const __bf16* __restrict__ Vb,
                                                unsigned char* __restrict__ WT)
{
    __shared__ __bf16 Vt[72][66];
    int bid = blockIdx.x;
    int sbu = bid >> 4, n0 = (bid & 15)*64;
    int tid = threadIdx.x;
    const __bf16* Vs = Vb + (size_t)sbu*65536;
    for (int idx = tid; idx < 576; idx += 256){
        int row = idx >> 3, ch = idx & 7;
        int n = (n0 - 4 + row) & 1023;
        bf16x8 v = ld8(Vs + (size_t)n*64 + ch*8);
        #pragma unroll
        for (int j=0;j<8;j++) Vt[row][ch*8+j] = v[j];
    }
    __syncthreads();
    int w = tid >> 6, l = tid & 63;
    unsigned char* dst = WT + (size_t)sbu*65536;
    int m = n0 + l;
    int kb = m >> 5, m32 = m & 31;
    int p = (m32 < 16) ? ((m32>>2)*8 + (m32&3))
                       : (((m32-16)>>2)*8 + 4 + (m32&3));
    size_t pbase = (size_t)kb*2048 + (p>>3)*128 + (p&7);
    #pragma unroll
    for (int it=0; it<16; it++){
        int d = it*4 + w;
        float sum = 0.f;
        #pragma unroll
        for (int j=0;j<5;j++) sum += (float)Vt[l + j*2][d];
        dst[pbase + (size_t)(d>>4)*512 + (d&15)*8] = tofp8(sum);
    }
}

// ---------------- attention (fp8 streams, P-centered) ----------------
// Block task = (s,b,h,dhi,qg): 4 waves x 32 q-rows, 1024 keys.
// S^T = mfma_fp8(K,Q); pack (exp2(s)-1) in fp8; O^T = mfma_fp8(W, P-1)
// + Wtot correction (sum_m 1*W). DS keeps exact f32 sum of exp.
__global__ __launch_bounds__(256) void attn_k(const unsigned char* __restrict__ Qb,
                                              const unsigned char* __restrict__ Kb,
                                              const unsigned char* __restrict__ WT,
                                              const float* __restrict__ Wtot,
                                              __bf16* __restrict__ pvp)
{
    int tid = threadIdx.x, wv = tid>>6, l = tid&63, lr = l&15, lg = l>>4;
    int t = blockIdx.x;
    int qg = t & 7; t >>= 3;
    int dhi = t & 3, h = (t>>2)&3, b = (t>>4)&1, s = (t>>5)&1;
    int dhv = (dhi==2) ? -1 : (dhi==3 ? 2 : dhi);   // {0,1,-1,2}
    int g = (h - dhv + 4) & 3;                      // K head
    int u = (h + dhv + 4) & 3;                      // V head
    int sb = s*2 + b;
    int nbase = qg*128 + wv*32;
    const unsigned char* Qw = Qb + ((size_t)(sb*4 + h))*65536 + (size_t)(nbase>>4)*1024;
    const unsigned char* Kg = Kb + ((size_t)(sb*4 + g))*65536;
    const unsigned char* Wu = WT + ((size_t)(sb*4 + u))*65536;
    i64 qa0 = ldl(Qw + l*8),        qa1 = ldl(Qw + 512 + l*8);
    i64 qb0 = ldl(Qw + 1024 + l*8), qb1 = ldl(Qw + 1536 + l*8);

    const f32x4 z = {0.f,0.f,0.f,0.f};
    f32x4 pvA[4] = {z,z,z,z};
    f32x4 pvB[4] = {z,z,z,z};
    float dsA = 0.f, dsB = 0.f;

    #pragma unroll 2
    for (int kt=0; kt<1024; kt+=32){
        const unsigned char* k0 = Kg + (size_t)(kt>>4)*1024 + l*8;
        i64 kf00 = ldl(k0),        kf01 = ldl(k0 + 512);
        i64 kf10 = ldl(k0 + 1024), kf11 = ldl(k0 + 1536);
        const unsigned char* w0 = Wu + (size_t)(kt>>5)*2048 + l*8;
        i64 wd0 = ldl(w0);
        i64 wd1 = ldl(w0 + 512);
        i64 wd2 = ldl(w0 + 1024);
        i64 wd3 = ldl(w0 + 1536);
        __builtin_amdgcn_s_setprio(1);
        f32x4 sA0 = MFMA8(kf00, qa0, z); sA0 = MFMA8(kf01, qa1, sA0);
        f32x4 sA1 = MFMA8(kf10, qa0, z); sA1 = MFMA8(kf11, qa1, sA1);
        f32x4 sB0 = MFMA8(kf00, qb0, z); sB0 = MFMA8(kf01, qb1, sB0);
        f32x4 sB1 = MFMA8(kf10, qb0, z); sB1 = MFMA8(kf11, qb1, sB1);
        __builtin_amdgcn_s_setprio(0);
        unsigned aLo=0, aHi=0, bLo=0, bHi=0;
        float eA0_0 = __builtin_amdgcn_exp2f(sA0[0]);
        float eA0_1 = __builtin_amdgcn_exp2f(sA0[1]);
        float eA0_2 = __builtin_amdgcn_exp2f(sA0[2]);
        float eA0_3 = __builtin_amdgcn_exp2f(sA0[3]);
        float eA1_0 = __builtin_amdgcn_exp2f(sA1[0]);
        float eA1_1 = __builtin_amdgcn_exp2f(sA1[1]);
        float eA1_2 = __builtin_amdgcn_exp2f(sA1[2]);
        float eA1_3 = __builtin_amdgcn_exp2f(sA1[3]);
        float eB0_0 = __builtin_amdgcn_exp2f(sB0[0]);
        float eB0_1 = __builtin_amdgcn_exp2f(sB0[1]);
        float eB0_2 = __builtin_amdgcn_exp2f(sB0[2]);
        float eB0_3 = __builtin_amdgcn_exp2f(sB0[3]);
        float eB1_0 = __builtin_amdgcn_exp2f(sB1[0]);
        float eB1_1 = __builtin_amdgcn_exp2f(sB1[1]);
        float eB1_2 = __builtin_amdgcn_exp2f(sB1[2]);
        float eB1_3 = __builtin_amdgcn_exp2f(sB1[3]);
        dsA += (eA0_0+eA0_1)+(eA0_2+eA0_3)+(eA1_0+eA1_1)+(eA1_2+eA1_3);
        dsB += (eB0_0+eB0_1)+(eB0_2+eB0_3)+(eB1_0+eB1_1)+(eB1_2+eB1_3);
        // pack CENTERED residual (e - 1): 6x smaller quantization error
        aLo = __builtin_amdgcn_cvt_pk_fp8_f32(eA0_0-1.f, eA0_1-1.f, aLo, false);
        aLo = __builtin_amdgcn_cvt_pk_fp8_f32(eA0_2-1.f, eA0_3-1.f, aLo, true);
        aHi = __builtin_amdgcn_cvt_pk_fp8_f32(eA1_0-1.f, eA1_1-1.f, aHi, false);
        aHi = __builtin_amdgcn_cvt_pk_fp8_f32(eA1_2-1.f, eA1_3-1.f, aHi, true);
        bLo = __builtin_amdgcn_cvt_pk_fp8_f32(eB0_0-1.f, eB0_1-1.f, bLo, false);
        bLo = __builtin_amdgcn_cvt_pk_fp8_f32(eB0_2-1.f, eB0_3-1.f, bLo, true);
        bHi = __builtin_amdgcn_cvt_pk_fp8_f32(eB1_0-1.f, eB1_1-1.f, bHi, false);
        bHi = __builtin_amdgcn_cvt_pk_fp8_f32(eB1_2-1.f, eB1_3-1.f, bHi, true);
        i64 paA = (i64)(((unsigned long long)aHi << 32) | aLo);
        i64 paB = (i64)(((unsigned long long)bHi << 32) | bLo);
        __builtin_amdgcn_s_setprio(1);
        pvA[0] = MFMA8(wd0, paA, pvA[0]);
        pvA[1] = MFMA8(wd1, paA, pvA[1]);
        pvA[2] = MFMA8(wd2, paA, pvA[2]);
        pvA[3] = MFMA8(wd3, paA, pvA[3]);
        pvB[0] = MFMA8(wd0, paB, pvB[0]);
        pvB[1] = MFMA8(wd1, paB, pvB[1]);
        pvB[2] = MFMA8(wd2, paB, pvB[2]);
        pvB[3] = MFMA8(wd3, paB, pvB[3]);
        __builtin_amdgcn_s_setprio(0);
    }
    dsA += __shfl_xor(dsA, 16, 64); dsA += __shfl_xor(dsA, 32, 64);
    dsB += __shfl_xor(dsB, 16, 64); dsB += __shfl_xor(dsB, 32, 64);
    float wgt = (dhi==3) ? 2.f : 1.f;
    float invA = wgt / dsA, invB = wgt / dsB;

    // rank-1 correction: O_unnorm += sum_m 1*W = Wtot (per d, all q-rows)
    const float* WtU = Wtot + (size_t)(sb*4 + u)*64;
    f32x4 wt[4];
    #pragma unroll
    for (int dt=0; dt<4; dt++)
        wt[dt] = *reinterpret_cast<const f32x4*>(WtU + dt*16 + lg*4);

    // stage normalized O-tile (32 rows x 64 cols) in per-wave LDS, stride 72
    __shared__ alignas(16) __bf16 ost[4][32*72];
    __bf16* S = ost[wv];
    #pragma unroll
    for (int dt=0; dt<4; dt++){
        bf16x4 oA, oB;
        #pragma unroll
        for (int i=0;i<4;i++){
            oA[i] = (__bf16)((pvA[dt][i] + wt[dt][i])*invA);
            oB[i] = (__bf16)((pvB[dt][i] + wt[dt][i])*invB);
        }
        int c0 = dt*16 + lg*4;
        *reinterpret_cast<bf16x4*>(S + lr*72 + c0)      = oA;
        *reinterpret_cast<bf16x4*>(S + (16+lr)*72 + c0) = oB;
    }
    int slot = s*4 + dhi;
    __bf16* pp = pvp + (size_t)slot*524288 + (size_t)b*262144 + (size_t)h*64;
    #pragma unroll
    for (int it=0; it<4; it++){
        int r = it*8 + (l>>3);
        bf16x8 v = *reinterpret_cast<const bf16x8*>(S + r*72 + (l&7)*8);
        *reinterpret_cast<bf16x8*>(pp + (size_t)(nbase + r)*256 + (l&7)*8) = v;
    }
}

// ------- reduce: out[b][n][c] = sum over 8 normalized slots ------------
__global__ __launch_bounds__(256) void reduce_k(const __bf16* __restrict__ pvp,
                                                float* __restrict__ out)
{
    int idx = blockIdx.x*256 + threadIdx.x;        // 0..65535
    size_t off = (size_t)idx*8;
    float acc[8] = {0,0,0,0,0,0,0,0};
    #pragma unroll
    for (int s4=0; s4<8; s4++){
        bf16x8 v = ld8(pvp + (size_t)s4*524288 + off);
        #pragma unroll
        for (int j=0;j<8;j++) acc[j] += (float)v[j];
    }
    f32x4 o0 = {acc[0],acc[1],acc[2],acc[3]};
    f32x4 o1 = {acc[4],acc[5],acc[6],acc[7]};
    *reinterpret_cast<f32x4*>(out + off)     = o0;
    *reinterpret_cast<f32x4*>(out + off + 4) = o1;
}

extern "C" void kernel_launch(void* const* d_in, const int* in_sizes, int n_in,
                              void* d_out, int out_size, void* d_ws, size_t ws_size,
                              hipStream_t stream)
{
    const float* x0 = (const float*)d_in[0];
    const float* x1 = (const float*)d_in[1];
    ProjArgs pa;
    for (int s=0;s<2;s++) for (int p=0;p<3;p++){
        pa.W[s*3+p]  = (const float*)d_in[2 + s*6 + p*2];
        pa.Bz[s*3+p] = (const float*)d_in[3 + s*6 + p*2];
    }
    char* wsb = (char*)d_ws;
    unsigned char* Qb = (unsigned char*)(wsb);            // 1 MB fp8 (fragment)
    unsigned char* Kb = (unsigned char*)(wsb + (1u<<20)); // 1 MB fp8
    __bf16* Vb = (__bf16*)(wsb + (2u<<20));               // 2 MB bf16 (natural)
    unsigned char* WT = (unsigned char*)(wsb + (4u<<20)); // 1 MB fp8 (sigma)
    __bf16* Xb = (__bf16*)(wsb + (5u<<20));               // 2 MB bf16 (fragment)
    __bf16* Wb = (__bf16*)(wsb + (7u<<20));               // 0.75 MB bf16
    __bf16* pvp = (__bf16*)(wsb + (8u<<20));              // 8 MB bf16, 8 slots
    float*  Wtot = (float*)(wsb + (16u<<20));             // 4 KB f32

    cvt_k<<<704, 256, 0, stream>>>(x0, x1, pa, Xb, Wb);
    proj_k<<<768, 256, 0, stream>>>(Xb, Wb, pa, Qb, Kb, Vb);
    vtot_k<<<16, 256, 0, stream>>>(Vb, Wtot);
    smooth_k<<<256, 256, 0, stream>>>(Vb, WT);
    attn_k<<<512, 256, 0, stream>>>(Qb, Kb, WT, Wtot, pvp);
    reduce_k<<<256, 256, 0, stream>>>(pvp, (float*)d_out);
}

// Round 15
// 49.876 us; speedup vs baseline: 1.1250x; 1.1250x over previous
//
#include <hip/hip_runtime.h>
#include <hip/hip_bf16.h>

// MultiScaleSparseSelfAttention, algebraically reduced (25 attn -> 4/head).
// R8 bf16 best: 47.9us. R13 all-fp8 failed absmax (0.0313). R14 P-centering:
//   absmax 0.0088 (PASS, quant error killed) but 56.1us — vtot_k was a
//   16-block serial-loop kernel on the critical path.
// R15: delete vtot_k. Wtot folded into smooth_k (V already staged in LDS:
//   partial-sum + atomicAdd, zeroed by cvt_k block 0). Everything else = R14.

typedef __bf16 bf16x8 __attribute__((ext_vector_type(8)));
typedef __bf16 bf16x4 __attribute__((ext_vector_type(4)));
typedef float f32x4 __attribute__((ext_vector_type(4)));
typedef long i64;

#define MFMA16(A,B,C) __builtin_amdgcn_mfma_f32_16x16x32_bf16(A,B,C,0,0,0)
#define MFMA8(A,B,C)  __builtin_amdgcn_mfma_f32_16x16x32_fp8_fp8(A,B,C,0,0,0)

__device__ __forceinline__ bf16x8 ld8(const __bf16* p){ return *reinterpret_cast<const bf16x8*>(p); }
__device__ __forceinline__ i64 ldl(const unsigned char* p){ return *reinterpret_cast<const i64*>(p); }
__device__ __forceinline__ unsigned char tofp8(float v){
    return (unsigned char)(__builtin_amdgcn_cvt_pk_fp8_f32(v, v, 0, false) & 0xff);
}

struct ProjArgs { const float* W[6]; const float* Bz[6]; };

// ---- cvt: f32 -> bf16 in FRAGMENT order; block 0 zeroes Wtot (4KB) ----
__global__ __launch_bounds__(256) void cvt_k(const float* __restrict__ x0,
                                             const float* __restrict__ x1,
                                             ProjArgs args,
                                             __bf16* __restrict__ Xb,
                                             __bf16* __restrict__ Wb,
                                             float* __restrict__ Wtot)
{
    int g = blockIdx.x*256 + threadIdx.x;
    if (blockIdx.x == 0){
        f32x4 zz = {0.f,0.f,0.f,0.f};
        *reinterpret_cast<f32x4*>(Wtot + threadIdx.x*4) = zz;
    }
    const float* src; __bf16* dst;
    if (g < 131072){                           // X part: s = g>>16
        int s = g >> 16;
        int E = (g & 65535)*8;                 // element offset within scale
        int blk = E >> 9, lane8 = (E >> 3) & 63;
        int row = (blk>>3)*16 + (lane8 & 15);
        int ci  = (blk&7)*32 + (lane8>>4)*8;
        src = (s ? x1 : x0) + (size_t)row*256 + ci;
        dst = Xb + (size_t)s*524288 + E;
    } else {
        int gw = g - 131072;                   // W part: sp = gw>>13
        int sp = gw >> 13;
        int E = (gw & 8191)*8;
        int blk = E >> 9, lane8 = (E >> 3) & 63;
        int co = (blk>>3)*16 + (lane8 & 15);
        int ci = (blk&7)*32 + (lane8>>4)*8;
        src = args.W[sp] + (size_t)co*256 + ci;
        dst = Wb + (size_t)sp*65536 + E;
    }
    f32x4 a = *reinterpret_cast<const f32x4*>(src);
    f32x4 b = *reinterpret_cast<const f32x4*>(src+4);
    bf16x8 o;
    #pragma unroll
    for (int j=0;j<4;j++){ o[j] = (__bf16)a[j]; o[4+j] = (__bf16)b[j]; }
    *reinterpret_cast<bf16x8*>(dst) = o;
}

// ---------------- projection ----------------
// 64x64 tile per block; q/k -> fp8 fragment order (4KB), v -> bf16 natural
// (8KB); staged in LDS, written as one contiguous region.
__global__ __launch_bounds__(256) void proj_k(const __bf16* __restrict__ Xb,
                                              const __bf16* __restrict__ Wb,
                                              ProjArgs args,
                                              unsigned char* __restrict__ Qb,
                                              unsigned char* __restrict__ Kb,
                                              __bf16* __restrict__ Vb)
{
    __shared__ alignas(16) unsigned char stage[8192];
    int bid = blockIdx.x;
    int cg = bid % 12, rg = bid / 12;
    int tid = threadIdx.x, wv = tid >> 6, l = tid & 63;
    int lr = l & 15, lg = l >> 4;
    int s = rg >> 5;
    const __bf16* Xf = Xb + (size_t)s*524288;
    int p = cg >> 2;                       // 0=q 1=k 2=v
    const __bf16* Wf = Wb + (size_t)(s*3+p)*65536;
    const float* bp = args.Bz[s*3 + p];
    int colbase = (cg & 3)*64;
    int rowblk = ((rg & 31)*4 + wv);

    f32x4 acc[4];
    #pragma unroll
    for (int t=0;t<4;t++) acc[t] = f32x4{0.f,0.f,0.f,0.f};

    #pragma unroll
    for (int kk=0; kk<8; kk++){
        bf16x8 af = ld8(Xf + (size_t)(rowblk*8 + kk)*512 + l*8);
        #pragma unroll
        for (int ct=0; ct<4; ct++){
            bf16x8 bfv = ld8(Wf + (size_t)(((cg&3)*4 + ct)*8 + kk)*512 + l*8);
            acc[ct] = MFMA16(af, bfv, acc[ct]);
        }
    }
    // sqrt((1/16)*log2 e) folded into BOTH q and k before fp8 quantization
    float qs = (p < 2) ? 0.30028057f : 1.0f;
    #pragma unroll
    for (int ct=0; ct<4; ct++){
        int d = ct*16 + lr;                      // 0..63 within head
        float bias = bp[colbase + d];
        #pragma unroll
        for (int i=0;i<4;i++){
            float v = (acc[ct][i] + bias) * qs;
            if (p < 2){
                int a = wv*1024 + ((d>>5)&1)*512 + ((d>>3)&3)*128 + (lg*4+i)*8 + (d&7);
                stage[a] = tofp8(v);
            } else {
                __bf16* sh = reinterpret_cast<__bf16*>(stage);
                sh[(wv*16 + lg*4 + i)*64 + d] = (__bf16)v;
            }
        }
    }
    __syncthreads();
    int gr0 = rg*64;
    int b = (gr0 >> 10) & 1, n0 = gr0 & 1023;
    int h = cg & 3;
    int sb = s*2 + b;
    if (p < 2){
        unsigned char* dstb = (p==0) ? Qb : Kb;
        size_t goff = ((size_t)(sb*4 + h))*65536 + (size_t)(n0>>4)*1024;
        uint4 v = *reinterpret_cast<const uint4*>(stage + tid*16);
        *reinterpret_cast<uint4*>(dstb + goff + (size_t)tid*16) = v;
    } else {
        size_t goff = ((size_t)(sb*4 + h)*1024 + n0)*64;
        const __bf16* sh = reinterpret_cast<const __bf16*>(stage);
        bf16x8 v0 = *reinterpret_cast<const bf16x8*>(sh + tid*16);
        bf16x8 v1 = *reinterpret_cast<const bf16x8*>(sh + tid*16 + 8);
        *reinterpret_cast<bf16x8*>(Vb + goff + (size_t)tid*16)     = v0;
        *reinterpret_cast<bf16x8*>(Vb + goff + (size_t)tid*16 + 8) = v1;
    }
}

// ------ smoothed V^T (fp8, sigma order) + Wtot accumulation ------
// Wtot[sbu][d] = 5 * sum_n V[n][d], accumulated per block via atomicAdd
// from the LDS-staged V tile (rows 4..67 = n0..n0+63).
__global__ __launch_bounds__(256) void smooth_k(const __bf16* __restrict__ Vb,
                                                unsigned char* __restrict__ WT,
                                                float* __restrict__ Wtot)
{
    __shared__ __bf16 Vt[72][66];
    __shared__ float vred[4][64];
    int bid = blockIdx.x;
    int sbu = bid >> 4, n0 = (bid & 15)*64;
    int tid = threadIdx.x;
    const __bf16* Vs = Vb + (size_t)sbu*65536;
    for (int idx = tid; idx < 576; idx += 256){
        int row = idx >> 3, ch = idx & 7;
        int n = (n0 - 4 + row) & 1023;
        bf16x8 v = ld8(Vs + (size_t)n*64 + ch*8);
        #pragma unroll
        for (int j=0;j<8;j++) Vt[row][ch*8+j] = v[j];
    }
    __syncthreads();
    int w = tid >> 6, l = tid & 63;
    // Wtot partial: seg w sums rows 4+w*16 .. 4+w*16+15 for channel l
    {
        float ps = 0.f;
        #pragma unroll
        for (int j=0;j<16;j++) ps += (float)Vt[4 + w*16 + j][l];
        vred[w][l] = ps;
    }
    unsigned char* dst = WT + (size_t)sbu*65536;
    int m = n0 + l;
    int kb = m >> 5, m32 = m & 31;
    int p = (m32 < 16) ? ((m32>>2)*8 + (m32&3))
                       : (((m32-16)>>2)*8 + 4 + (m32&3));
    size_t pbase = (size_t)kb*2048 + (p>>3)*128 + (p&7);
    #pragma unroll
    for (int it=0; it<16; it++){
        int d = it*4 + w;
        float sum = 0.f;
        #pragma unroll
        for (int j=0;j<5;j++) sum += (float)Vt[l + j*2][d];
        dst[pbase + (size_t)(d>>4)*512 + (d&15)*8] = tofp8(sum);
    }
    __syncthreads();
    if (w == 0)
        atomicAdd(Wtot + (size_t)sbu*64 + l,
                  5.f*(vred[0][l]+vred[1][l]+vred[2][l]+vred[3][l]));
}

// ---------------- attention (fp8 streams, P-centered) ----------------
// Block task = (s,b,h,dhi,qg): 4 waves x 32 q-rows, 1024 keys.
// S^T = mfma_fp8(K,Q); pack (exp2(s)-1) in fp8; O^T = mfma_fp8(W, P-1)
// + Wtot correction (sum_m 1*W). DS keeps exact f32 sum of exp.
__global__ __launch_bounds__(256) void attn_k(const unsigned char* __restrict__ Qb,
                                              const unsigned char* __restrict__ Kb,
                                              const unsigned char* __restrict__ WT,
                                              const float* __restrict__ Wtot,
                                              __bf16* __restrict__ pvp)
{
    int tid = threadIdx.x, wv = tid>>6, l = tid&63, lr = l&15, lg = l>>4;
    int t = blockIdx.x;
    int qg = t & 7; t >>= 3;
    int dhi = t & 3, h = (t>>2)&3, b = (t>>4)&1, s = (t>>5)&1;
    int dhv = (dhi==2) ? -1 : (dhi==3 ? 2 : dhi);   // {0,1,-1,2}
    int g = (h - dhv + 4) & 3;                      // K head
    int u = (h + dhv + 4) & 3;                      // V head
    int sb = s*2 + b;
    int nbase = qg*128 + wv*32;
    const unsigned char* Qw = Qb + ((size_t)(sb*4 + h))*65536 + (size_t)(nbase>>4)*1024;
    const unsigned char* Kg = Kb + ((size_t)(sb*4 + g))*65536;
    const unsigned char* Wu = WT + ((size_t)(sb*4 + u))*65536;
    i64 qa0 = ldl(Qw + l*8),        qa1 = ldl(Qw + 512 + l*8);
    i64 qb0 = ldl(Qw + 1024 + l*8), qb1 = ldl(Qw + 1536 + l*8);

    const f32x4 z = {0.f,0.f,0.f,0.f};
    f32x4 pvA[4] = {z,z,z,z};
    f32x4 pvB[4] = {z,z,z,z};
    float dsA = 0.f, dsB = 0.f;

    #pragma unroll 2
    for (int kt=0; kt<1024; kt+=32){
        const unsigned char* k0 = Kg + (size_t)(kt>>4)*1024 + l*8;
        i64 kf00 = ldl(k0),        kf01 = ldl(k0 + 512);
        i64 kf10 = ldl(k0 + 1024), kf11 = ldl(k0 + 1536);
        const unsigned char* w0 = Wu + (size_t)(kt>>5)*2048 + l*8;
        i64 wd0 = ldl(w0);
        i64 wd1 = ldl(w0 + 512);
        i64 wd2 = ldl(w0 + 1024);
        i64 wd3 = ldl(w0 + 1536);
        __builtin_amdgcn_s_setprio(1);
        f32x4 sA0 = MFMA8(kf00, qa0, z); sA0 = MFMA8(kf01, qa1, sA0);
        f32x4 sA1 = MFMA8(kf10, qa0, z); sA1 = MFMA8(kf11, qa1, sA1);
        f32x4 sB0 = MFMA8(kf00, qb0, z); sB0 = MFMA8(kf01, qb1, sB0);
        f32x4 sB1 = MFMA8(kf10, qb0, z); sB1 = MFMA8(kf11, qb1, sB1);
        __builtin_amdgcn_s_setprio(0);
        unsigned aLo=0, aHi=0, bLo=0, bHi=0;
        float eA0_0 = __builtin_amdgcn_exp2f(sA0[0]);
        float eA0_1 = __builtin_amdgcn_exp2f(sA0[1]);
        float eA0_2 = __builtin_amdgcn_exp2f(sA0[2]);
        float eA0_3 = __builtin_amdgcn_exp2f(sA0[3]);
        float eA1_0 = __builtin_amdgcn_exp2f(sA1[0]);
        float eA1_1 = __builtin_amdgcn_exp2f(sA1[1]);
        float eA1_2 = __builtin_amdgcn_exp2f(sA1[2]);
        float eA1_3 = __builtin_amdgcn_exp2f(sA1[3]);
        float eB0_0 = __builtin_amdgcn_exp2f(sB0[0]);
        float eB0_1 = __builtin_amdgcn_exp2f(sB0[1]);
        float eB0_2 = __builtin_amdgcn_exp2f(sB0[2]);
        float eB0_3 = __builtin_amdgcn_exp2f(sB0[3]);
        float eB1_0 = __builtin_amdgcn_exp2f(sB1[0]);
        float eB1_1 = __builtin_amdgcn_exp2f(sB1[1]);
        float eB1_2 = __builtin_amdgcn_exp2f(sB1[2]);
        float eB1_3 = __builtin_amdgcn_exp2f(sB1[3]);
        dsA += (eA0_0+eA0_1)+(eA0_2+eA0_3)+(eA1_0+eA1_1)+(eA1_2+eA1_3);
        dsB += (eB0_0+eB0_1)+(eB0_2+eB0_3)+(eB1_0+eB1_1)+(eB1_2+eB1_3);
        // pack CENTERED residual (e - 1): 6x smaller quantization error
        aLo = __builtin_amdgcn_cvt_pk_fp8_f32(eA0_0-1.f, eA0_1-1.f, aLo, false);
        aLo = __builtin_amdgcn_cvt_pk_fp8_f32(eA0_2-1.f, eA0_3-1.f, aLo, true);
        aHi = __builtin_amdgcn_cvt_pk_fp8_f32(eA1_0-1.f, eA1_1-1.f, aHi, false);
        aHi = __builtin_amdgcn_cvt_pk_fp8_f32(eA1_2-1.f, eA1_3-1.f, aHi, true);
        bLo = __builtin_amdgcn_cvt_pk_fp8_f32(eB0_0-1.f, eB0_1-1.f, bLo, false);
        bLo = __builtin_amdgcn_cvt_pk_fp8_f32(eB0_2-1.f, eB0_3-1.f, bLo, true);
        bHi = __builtin_amdgcn_cvt_pk_fp8_f32(eB1_0-1.f, eB1_1-1.f, bHi, false);
        bHi = __builtin_amdgcn_cvt_pk_fp8_f32(eB1_2-1.f, eB1_3-1.f, bHi, true);
        i64 paA = (i64)(((unsigned long long)aHi << 32) | aLo);
        i64 paB = (i64)(((unsigned long long)bHi << 32) | bLo);
        __builtin_amdgcn_s_setprio(1);
        pvA[0] = MFMA8(wd0, paA, pvA[0]);
        pvA[1] = MFMA8(wd1, paA, pvA[1]);
        pvA[2] = MFMA8(wd2, paA, pvA[2]);
        pvA[3] = MFMA8(wd3, paA, pvA[3]);
        pvB[0] = MFMA8(wd0, paB, pvB[0]);
        pvB[1] = MFMA8(wd1, paB, pvB[1]);
        pvB[2] = MFMA8(wd2, paB, pvB[2]);
        pvB[3] = MFMA8(wd3, paB, pvB[3]);
        __builtin_amdgcn_s_setprio(0);
    }
    dsA += __shfl_xor(dsA, 16, 64); dsA += __shfl_xor(dsA, 32, 64);
    dsB += __shfl_xor(dsB, 16, 64); dsB += __shfl_xor(dsB, 32, 64);
    float wgt = (dhi==3) ? 2.f : 1.f;
    float invA = wgt / dsA, invB = wgt / dsB;

    // rank-1 correction: O_unnorm += sum_m 1*W = Wtot (per d, all q-rows)
    const float* WtU = Wtot + (size_t)(sb*4 + u)*64;
    f32x4 wt[4];
    #pragma unroll
    for (int dt=0; dt<4; dt++)
        wt[dt] = *reinterpret_cast<const f32x4*>(WtU + dt*16 + lg*4);

    // stage normalized O-tile (32 rows x 64 cols) in per-wave LDS, stride 72
    __shared__ alignas(16) __bf16 ost[4][32*72];
    __bf16* S = ost[wv];
    #pragma unroll
    for (int dt=0; dt<4; dt++){
        bf16x4 oA, oB;
        #pragma unroll
        for (int i=0;i<4;i++){
            oA[i] = (__bf16)((pvA[dt][i] + wt[dt][i])*invA);
            oB[i] = (__bf16)((pvB[dt][i] + wt[dt][i])*invB);
        }
        int c0 = dt*16 + lg*4;
        *reinterpret_cast<bf16x4*>(S + lr*72 + c0)      = oA;
        *reinterpret_cast<bf16x4*>(S + (16+lr)*72 + c0) = oB;
    }
    int slot = s*4 + dhi;
    __bf16* pp = pvp + (size_t)slot*524288 + (size_t)b*262144 + (size_t)h*64;
    #pragma unroll
    for (int it=0; it<4; it++){
        int r = it*8 + (l>>3);
        bf16x8 v = *reinterpret_cast<const bf16x8*>(S + r*72 + (l&7)*8);
        *reinterpret_cast<bf16x8*>(pp + (size_t)(nbase + r)*256 + (l&7)*8) = v;
    }
}

// ------- reduce: out[b][n][c] = sum over 8 normalized slots ------------
__global__ __launch_bounds__(256) void reduce_k(const __bf16* __restrict__ pvp,
                                                float* __restrict__ out)
{
    int idx = blockIdx.x*256 + threadIdx.x;        // 0..65535
    size_t off = (size_t)idx*8;
    float acc[8] = {0,0,0,0,0,0,0,0};
    #pragma unroll
    for (int s4=0; s4<8; s4++){
        bf16x8 v = ld8(pvp + (size_t)s4*524288 + off);
        #pragma unroll
        for (int j=0;j<8;j++) acc[j] += (float)v[j];
    }
    f32x4 o0 = {acc[0],acc[1],acc[2],acc[3]};
    f32x4 o1 = {acc[4],acc[5],acc[6],acc[7]};
    *reinterpret_cast<f32x4*>(out + off)     = o0;
    *reinterpret_cast<f32x4*>(out + off + 4) = o1;
}

extern "C" void kernel_launch(void* const* d_in, const int* in_sizes, int n_in,
                              void* d_out, int out_size, void* d_ws, size_t ws_size,
                              hipStream_t stream)
{
    const float* x0 = (const float*)d_in[0];
    const float* x1 = (const float*)d_in[1];
    ProjArgs pa;
    for (int s=0;s<2;s++) for (int p=0;p<3;p++){
        pa.W[s*3+p]  = (const float*)d_in[2 + s*6 + p*2];
        pa.Bz[s*3+p] = (const float*)d_in[3 + s*6 + p*2];
    }
    char* wsb = (char*)d_ws;
    unsigned char* Qb = (unsigned char*)(wsb);            // 1 MB fp8 (fragment)
    unsigned char* Kb = (unsigned char*)(wsb + (1u<<20)); // 1 MB fp8
    __bf16* Vb = (__bf16*)(wsb + (2u<<20));               // 2 MB bf16 (natural)
    unsigned char* WT = (unsigned char*)(wsb + (4u<<20)); // 1 MB fp8 (sigma)
    __bf16* Xb = (__bf16*)(wsb + (5u<<20));               // 2 MB bf16 (fragment)
    __bf16* Wb = (__bf16*)(wsb + (7u<<20));               // 0.75 MB bf16
    __bf16* pvp = (__bf16*)(wsb + (8u<<20));              // 8 MB bf16, 8 slots
    float*  Wtot = (float*)(wsb + (16u<<20));             // 4 KB f32

    cvt_k<<<704, 256, 0, stream>>>(x0, x1, pa, Xb, Wb, Wtot);
    proj_k<<<768, 256, 0, stream>>>(Xb, Wb, pa, Qb, Kb, Vb);
    smooth_k<<<256, 256, 0, stream>>>(Vb, WT, Wtot);
    attn_k<<<512, 256, 0, stream>>>(Qb, Kb, WT, Wtot, pvp);
    reduce_k<<<256, 256, 0, stream>>>(pvp, (float*)d_out);
}